// Round 19
// baseline (156.778 us; speedup 1.0000x reference)
//
#include <hip/hip_runtime.h>

// Problem constants (fixed by setup_inputs)
#define T_ 4
#define B_ 4
#define CK 128
#define CV 512
#define PP 4096   // H*W = 64*64
#define QQ 1024   // h*w = 32*32
#define MM 4096   // T*h*w
#define NS 4      // gattn K-split factor

using f32x2  = __attribute__((ext_vector_type(2))) float;
using f32x4  = __attribute__((ext_vector_type(4))) float;
using bf16   = __bf16;
using bf16x2 = __attribute__((ext_vector_type(2))) __bf16;
using bf16x4 = __attribute__((ext_vector_type(4))) __bf16;
using bf16x8 = __attribute__((ext_vector_type(8))) __bf16;
using f16    = _Float16;
using f16x8  = __attribute__((ext_vector_type(8))) _Float16;

__device__ __forceinline__ f32x4 mfma16(bf16x8 a, bf16x8 b, f32x4 c) {
    return __builtin_amdgcn_mfma_f32_16x16x32_bf16(a, b, c, 0, 0, 0);
}
__device__ __forceinline__ f32x4 mfma16h(f16x8 a, f16x8 b, f32x4 c) {
    return __builtin_amdgcn_mfma_f32_16x16x32_f16(a, b, c, 0, 0, 0);
}

// async global->LDS DMA, 16B per lane, dest = uniform base + lane*16
__device__ __forceinline__ void gload16(const void* g, void* l) {
    __builtin_amdgcn_global_load_lds(
        (const __attribute__((address_space(1))) void*)g,
        (__attribute__((address_space(3))) void*)l, 16, 0, 0);
}

// ===========================================================================
// STAGE 1 (1:1 even/odd interleave, deep stream blocks):
//   even bid -> logits GEMM (1024 blocks) -> Pt, cs_part
//   odd  bid -> sid = bid>>1:
//     [0,512)    mv  f32 -> mvh f16   (512 KB contiguous tile, 32 iters)
//     [512,640)  mk  f32 -> mkh f16
//     [640,768)  mvl f32 -> Ab  bf16
//     [768,896)  qv 2x2 avg-pool -> QVp (f32x4 reads)
//     else       idle
// grid 2048 ~= all-resident at ~4 blocks/CU -> stable role mix per CU.
// ===========================================================================
__global__ __launch_bounds__(256) void k_stage1(
        const float* __restrict__ mkl, const float* __restrict__ qkl,
        bf16* __restrict__ Pt, float* __restrict__ cs_part,
        const float* __restrict__ mvl, bf16* __restrict__ Ab,
        const float* __restrict__ qv,  float* __restrict__ qvp,
        const float* __restrict__ mk,  f16* __restrict__ mkh,
        const float* __restrict__ mv,  f16* __restrict__ mvh) {
    __shared__ __align__(16) char smem[20480];
    const int bid = blockIdx.x;
    const int tid = threadIdx.x;

    if ((bid & 1) == 0) {
        // ---- logits: L = mkl^T qkl, exp, colsums, transpose -> Pt -----------
        bf16* As = (bf16*)smem;              // [128][40]
        bf16* Bs = (bf16*)(smem + 10240);    // [128][40]
        bf16* Th = (bf16*)smem;              // [128][72] half-transpose (union)

        int lb  = bid >> 1;                  // 0..1023
        int sw  = (lb & 7) * 128 + (lb >> 3);
        const int b  = sw >> 8;
        const int r  = sw & 255;
        const int qy = r >> 5;
        const int mx = r & 31;
        const int m0 = mx * 128;
        const int q0 = qy * 128;
        const int t  = m0 >> 10;
        const int sm0 = m0 & 1023;

        const int lane = tid & 63;
        const int wid  = tid >> 6;
        const int wr = wid >> 1, wc = wid & 1;
        const int g = lane >> 4, li = lane & 15;

        const float* Abase = mkl + (((size_t)(t * B_ + b) * CK) << 10) + sm0;
        const float* Bbase = qkl + (((size_t)b * CK) << 10) + q0;
        const int ml   = tid & 127;
        const int half = tid >> 7;

        const f32x4 fz = {0.f, 0.f, 0.f, 0.f};
        f32x4 acc[4][4];
#pragma unroll
        for (int i = 0; i < 4; ++i)
#pragma unroll
            for (int j = 0; j < 4; ++j) acc[i][j] = fz;

        for (int k0 = 0; k0 < CK; k0 += 32) {
#pragma unroll
            for (int j = 0; j < 8; ++j) {
                int kk = 4 * j + 2 * half;
                float a0 = Abase[(k0 + kk) * 1024 + ml];
                float a1 = Abase[(k0 + kk + 1) * 1024 + ml];
                bf16x2 pa; pa.x = (bf16)a0; pa.y = (bf16)a1;
                *(bf16x2*)(As + ml * 40 + kk) = pa;
                float b0 = Bbase[(k0 + kk) * 1024 + ml];
                float b1 = Bbase[(k0 + kk + 1) * 1024 + ml];
                bf16x2 pb; pb.x = (bf16)b0; pb.y = (bf16)b1;
                *(bf16x2*)(Bs + ml * 40 + kk) = pb;
            }
            __syncthreads();
            bf16x8 af[4], bfr[4];
#pragma unroll
            for (int mf = 0; mf < 4; ++mf)
                af[mf] = *(const bf16x8*)(As + (wr * 64 + mf * 16 + li) * 40 + g * 8);
#pragma unroll
            for (int nf = 0; nf < 4; ++nf)
                bfr[nf] = *(const bf16x8*)(Bs + (wc * 64 + nf * 16 + li) * 40 + g * 8);
#pragma unroll
            for (int mf = 0; mf < 4; ++mf)
#pragma unroll
                for (int nf = 0; nf < 4; ++nf)
                    acc[mf][nf] = mfma16(af[mf], bfr[nf], acc[mf][nf]);
            __syncthreads();
        }

        float cs[4] = {0.f, 0.f, 0.f, 0.f};
        bf16x4 ebuf[4][4];
#pragma unroll
        for (int mf = 0; mf < 4; ++mf)
#pragma unroll
            for (int nf = 0; nf < 4; ++nf) {
                f32x4 v = acc[mf][nf];
                float e0 = __expf(v.x), e1 = __expf(v.y);
                float e2 = __expf(v.z), e3 = __expf(v.w);
                cs[nf] += e0 + e1 + e2 + e3;
                bf16x4 e; e.x = (bf16)e0; e.y = (bf16)e1; e.z = (bf16)e2; e.w = (bf16)e3;
                ebuf[mf][nf] = e;
            }
#pragma unroll
        for (int nf = 0; nf < 4; ++nf) {
            float s = cs[nf];
            s += __shfl_xor(s, 16);
            s += __shfl_xor(s, 32);
            if (g == 0)
                cs_part[(size_t)(((b * 32 + mx) * 2 + wr) << 10) + q0 + wc * 64 + nf * 16 + li] = s;
        }
#pragma unroll
        for (int p = 0; p < 2; ++p) {
            __syncthreads();
            if (wr == p) {
#pragma unroll
                for (int mf = 0; mf < 4; ++mf)
#pragma unroll
                    for (int nf = 0; nf < 4; ++nf) {
                        int col  = wc * 64 + nf * 16 + li;
                        int rowb = mf * 16 + g * 4;
                        *(bf16x4*)(Th + col * 72 + rowb) = ebuf[mf][nf];
                    }
            }
            __syncthreads();
#pragma unroll
            for (int pass = 0; pass < 4; ++pass) {
                int idx = pass * 256 + tid;
                int row = idx >> 3;
                int ch  = (idx & 7) * 8;
                bf16x8 v = *(const bf16x8*)(Th + row * 72 + ch);
                *(bf16x8*)(Pt + (size_t)(b * QQ + q0 + row) * MM + m0 + p * 64 + ch) = v;
            }
        }
    } else {
        int sid = bid >> 1;                    // 0..1023
        if (sid < 512) {
            // ---- mv -> mvh : 4,194,304 chunks, 512 blocks x 32 iters --------
            int base = sid * 8192 + tid;
#pragma unroll
            for (int i = 0; i < 32; ++i) {
                int idx = base + i * 256;
                f32x4 a = __builtin_nontemporal_load((const f32x4*)mv + (size_t)idx * 2);
                f32x4 c = __builtin_nontemporal_load((const f32x4*)mv + (size_t)idx * 2 + 1);
                f16x8 o;
                o[0] = (f16)a.x; o[1] = (f16)a.y; o[2] = (f16)a.z; o[3] = (f16)a.w;
                o[4] = (f16)c.x; o[5] = (f16)c.y; o[6] = (f16)c.z; o[7] = (f16)c.w;
                ((f16x8*)mvh)[idx] = o;
            }
        } else if (sid < 640) {
            // ---- mk -> mkh : 1,048,576 chunks, 128 blocks x 32 iters --------
            int base = (sid - 512) * 8192 + tid;
#pragma unroll
            for (int i = 0; i < 32; ++i) {
                int idx = base + i * 256;
                f32x4 a = __builtin_nontemporal_load((const f32x4*)mk + (size_t)idx * 2);
                f32x4 c = __builtin_nontemporal_load((const f32x4*)mk + (size_t)idx * 2 + 1);
                f16x8 o;
                o[0] = (f16)a.x; o[1] = (f16)a.y; o[2] = (f16)a.z; o[3] = (f16)a.w;
                o[4] = (f16)c.x; o[5] = (f16)c.y; o[6] = (f16)c.z; o[7] = (f16)c.w;
                ((f16x8*)mkh)[idx] = o;
            }
        } else if (sid < 768) {
            // ---- mvl -> Ab bf16 : 128 blocks x 32 iters ---------------------
            int base = (sid - 640) * 8192 + tid;
#pragma unroll
            for (int i = 0; i < 32; ++i) {
                int idx = base + i * 256;
                f32x4 a = __builtin_nontemporal_load((const f32x4*)mvl + (size_t)idx * 2);
                f32x4 c = __builtin_nontemporal_load((const f32x4*)mvl + (size_t)idx * 2 + 1);
                bf16x8 o;
                o[0] = (bf16)a.x; o[1] = (bf16)a.y; o[2] = (bf16)a.z; o[3] = (bf16)a.w;
                o[4] = (bf16)c.x; o[5] = (bf16)c.y; o[6] = (bf16)c.z; o[7] = (bf16)c.w;
                ((bf16x8*)Ab)[idx] = o;
            }
        } else if (sid < 896) {
            // ---- qv 2x2 avg-pool : 1,048,576 pairs, 128 blocks x 32 iters ---
            int base = (sid - 768) * 8192 + tid;
#pragma unroll
            for (int i = 0; i < 32; ++i) {
                int pidx = base + i * 256;
                int pr = pidx & 511;
                int bv = pidx >> 9;
                int y = pr >> 4, xp = pr & 15;
                const float* src = qv + ((size_t)bv << 12) + y * 128 + xp * 4;
                f32x4 r0 = __builtin_nontemporal_load((const f32x4*)src);
                f32x4 r1 = __builtin_nontemporal_load((const f32x4*)(src + 64));
                f32x2 o;
                o.x = 0.25f * (r0.x + r0.y + r1.x + r1.y);
                o.y = 0.25f * (r0.z + r0.w + r1.z + r1.w);
                *(f32x2*)(qvp + ((size_t)bv << 10) + y * 32 + xp * 2) = o;
            }
        }
        // else: idle filler block
    }
}

// ===========================================================================
// STAGE 2:  [0,256)     gattn GEMM (f16 data, NS=4) -> Gp
//           [256,768)   memory GEMM -> Mp
//           [768,784)   colsum reduce
// ===========================================================================
__global__ __launch_bounds__(256, 2) void k_stage2(
        const f16* __restrict__ mkh, const f16* __restrict__ mvh,
        float* __restrict__ Gp,
        const bf16* __restrict__ Ab, const bf16* __restrict__ Pt,
        float* __restrict__ Mp,
        const float* __restrict__ cs_part, float* __restrict__ colsum) {
    __shared__ __align__(16) char smem[65536];
    const int bid = blockIdx.x;
    const int tid = threadIdx.x;

    if (bid < 256) {
        // ---- gattn: G[k][v] = sum_p mkh*mvh  (f16 MFMA), NS=4 ---------------
        f16* lsA = (f16*)smem;               // [2][128*64]
        f16* lsB = (f16*)(smem + 32768);

        int sw  = (bid & 7) * 32 + (bid >> 3);
        const int bt = sw >> 4;
        const int rx = sw & 15;
        const int ks = rx >> 2;              // 0..3, p-range [ks*1024, +1024)
        const int v0 = (rx & 3) * 128;
        const int b = bt >> 2, t = bt & 3;

        const int lane = tid & 63;
        const int w    = tid >> 6;
        const int wr = w >> 1, wc = w & 1;
        const int g = lane >> 4, li = lane & 15;
        const int rr = lane >> 3;
        const int cg = (lane & 7) ^ rr;

        const f16* Abase = mkh + ((size_t)(t * B_ + b) * CK) * PP + ks * 1024;
        const f16* Bbase = mvh + ((size_t)((t * B_ + b) * CV + v0)) * PP + ks * 1024;

        auto STAGE = [&](int buf, int j) {
            int mg = j * 64;
#pragma unroll
            for (int cc = 0; cc < 4; ++cc) {
                int c = cc * 4 + w;
                int r = c * 8 + rr;
                gload16(Abase + (size_t)r * PP + mg + cg * 8, lsA + buf * 8192 + c * 512);
                gload16(Bbase + (size_t)r * PP + mg + cg * 8, lsB + buf * 8192 + c * 512);
            }
        };
        auto FRAG = [&](const f16* base, int r, int G) -> f16x8 {
            int x = r & 7;
            return *(const f16x8*)(base + (r >> 3) * 512 + x * 64 + ((G ^ x) * 8));
        };

        const f32x4 fz = {0.f, 0.f, 0.f, 0.f};
        f32x4 acc[4][4];
#pragma unroll
        for (int i = 0; i < 4; ++i)
#pragma unroll
            for (int j = 0; j < 4; ++j) acc[i][j] = fz;

        STAGE(0, 0);
        __syncthreads();
        int cur = 0;

        for (int j = 0; j < 16; ++j) {
            if (j + 1 < 16) STAGE(cur ^ 1, j + 1);
#pragma unroll
            for (int kc = 0; kc < 2; ++kc) {
                f16x8 af[4], bfr[4];
#pragma unroll
                for (int mf = 0; mf < 4; ++mf)
                    af[mf] = FRAG(lsA + cur * 8192, wr * 64 + mf * 16 + li, kc * 4 + g);
#pragma unroll
                for (int nf = 0; nf < 4; ++nf)
                    bfr[nf] = FRAG(lsB + cur * 8192, wc * 64 + nf * 16 + li, kc * 4 + g);
#pragma unroll
                for (int mf = 0; mf < 4; ++mf)
#pragma unroll
                    for (int nf = 0; nf < 4; ++nf)
                        acc[mf][nf] = mfma16h(af[mf], bfr[nf], acc[mf][nf]);
            }
            __syncthreads();
            cur ^= 1;
        }

        float* outp = Gp + (size_t)(ks * 16 + bt) * CK * CV + v0;
#pragma unroll
        for (int mf = 0; mf < 4; ++mf)
#pragma unroll
            for (int nf = 0; nf < 4; ++nf) {
                int k = wr * 64 + mf * 16 + g * 4;
                int v = wc * 64 + nf * 16 + li;
                f32x4 a = acc[mf][nf];
                outp[(size_t)(k + 0) * CV + v] = a.x;
                outp[(size_t)(k + 1) * CV + v] = a.y;
                outp[(size_t)(k + 2) * CV + v] = a.z;
                outp[(size_t)(k + 3) * CV + v] = a.w;
            }
    } else if (bid < 768) {
        // ---- memory: Mp = Ab x Pt (bf16 MFMA) -------------------------------
        bf16* lsA = (bf16*)smem;             // [2][128*64]
        bf16* lsB = (bf16*)(smem + 32768);

        int mb = bid - 256;
        int sw  = (mb & 7) * 64 + (mb >> 3);
        const int bt = sw >> 5;
        const int rx = sw & 31;
        const int q0 = (rx >> 2) * 128;
        const int v0 = (rx & 3) * 128;
        const int b = bt >> 2, t = bt & 3;

        const int lane = tid & 63;
        const int w    = tid >> 6;
        const int wr = w >> 1, wc = w & 1;
        const int g = lane >> 4, li = lane & 15;
        const int rr = lane >> 3;
        const int cg = (lane & 7) ^ rr;

        const bf16* Abase = Ab + (((size_t)((t * B_ + b) * CV + v0)) << 10);
        const bf16* Bbase = Pt + (size_t)(b * QQ + q0) * MM + t * 1024;

        auto STAGE = [&](int buf, int j) {
            int mg = j * 64;
#pragma unroll
            for (int cc = 0; cc < 4; ++cc) {
                int c = cc * 4 + w;
                int r = c * 8 + rr;
                gload16(Abase + (size_t)r * 1024 + mg + cg * 8, lsA + buf * 8192 + c * 512);
                gload16(Bbase + (size_t)r * MM   + mg + cg * 8, lsB + buf * 8192 + c * 512);
            }
        };
        auto FRAG = [&](const bf16* base, int r, int G) -> bf16x8 {
            int x = r & 7;
            return *(const bf16x8*)(base + (r >> 3) * 512 + x * 64 + ((G ^ x) * 8));
        };

        const f32x4 fz = {0.f, 0.f, 0.f, 0.f};
        f32x4 acc[4][4];
#pragma unroll
        for (int i = 0; i < 4; ++i)
#pragma unroll
            for (int j = 0; j < 4; ++j) acc[i][j] = fz;

        STAGE(0, 0);
        __syncthreads();
        int cur = 0;

        for (int j = 0; j < 16; ++j) {
            if (j + 1 < 16) STAGE(cur ^ 1, j + 1);
#pragma unroll
            for (int kc = 0; kc < 2; ++kc) {
                bf16x8 af[4], bfr[4];
#pragma unroll
                for (int mf = 0; mf < 4; ++mf)
                    af[mf] = FRAG(lsA + cur * 8192, wr * 64 + mf * 16 + li, kc * 4 + g);
#pragma unroll
                for (int nf = 0; nf < 4; ++nf)
                    bfr[nf] = FRAG(lsB + cur * 8192, wc * 64 + nf * 16 + li, kc * 4 + g);
#pragma unroll
                for (int mf = 0; mf < 4; ++mf)
#pragma unroll
                    for (int nf = 0; nf < 4; ++nf)
                        acc[mf][nf] = mfma16(af[mf], bfr[nf], acc[mf][nf]);
            }
            __syncthreads();
            cur ^= 1;
        }

#pragma unroll
        for (int nf = 0; nf < 4; ++nf) {
            int q = q0 + wc * 64 + nf * 16 + li;
#pragma unroll
            for (int mf = 0; mf < 4; ++mf) {
                int v = v0 + wr * 64 + mf * 16 + g * 4;
                f32x4 a = acc[mf][nf];
                float* base = Mp + (((size_t)bt * CV + v) << 10) + q;
                base[0 << 10] = a.x;
                base[1 << 10] = a.y;
                base[2 << 10] = a.z;
                base[3 << 10] = a.w;
            }
        }
    } else {
        // ---- colsum: sum 64 partial rows ------------------------------------
        int idx = (bid - 768) * 256 + tid;   // B*QQ = 4096
        int q = idx & (QQ - 1);
        int b = idx >> 10;
        float s = 0.f;
#pragma unroll 8
        for (int r = 0; r < 64; ++r)
            s += cs_part[(size_t)(((b * 64 + r)) << 10) + q];
        colsum[idx] = s;
    }
}

// ===========================================================================
// STAGE 3:  [0,1024)     softT: reduce NS partials + softmax over T -> Wt
//           [1024,3072)  reduce: out[512..1023] = sum_t Mp / colsum
// ===========================================================================
__global__ __launch_bounds__(256) void k_stage3(
        const float* __restrict__ Gp, bf16* __restrict__ Wt,
        const float* __restrict__ Mp, const float* __restrict__ colsum,
        float* __restrict__ out) {
    const int bid = blockIdx.x;
    const int tid = threadIdx.x;

    if (bid < 1024) {
        int idx = bid * 256 + tid;             // B*CK*CV = 262144
        int v = idx & (CV - 1);
        int bk = idx >> 9;
        int k = bk & (CK - 1);
        int b = bk >> 7;
        float gv[4];
#pragma unroll
        for (int t = 0; t < 4; ++t) {
            float s = 0.f;
#pragma unroll
            for (int ks = 0; ks < NS; ++ks)
                s += Gp[((size_t)(ks * 16 + b * 4 + t) * CK + k) * CV + v];
            gv[t] = s;
        }
        float mx = fmaxf(fmaxf(gv[0], gv[1]), fmaxf(gv[2], gv[3]));
        float e[4], sum = 0.f;
#pragma unroll
        for (int t = 0; t < 4; ++t) { e[t] = __expf(gv[t] - mx); sum += e[t]; }
        float inv = 1.f / sum;
#pragma unroll
        for (int t = 0; t < 4; ++t)
            Wt[((size_t)((b * 4 + t) * CK + k)) * CV + v] = (bf16)(e[t] * inv);
    } else {
        int idx = ((bid - 1024) * 256 + tid) * 4;   // over B*CV*QQ = 2M
        int q = idx & (QQ - 1);
        int v = (idx >> 10) & (CV - 1);
        int b = idx >> 19;
        f32x4 s = {0.f, 0.f, 0.f, 0.f};
#pragma unroll
        for (int t = 0; t < 4; ++t) {
            f32x4 m = *(const f32x4*)(Mp + (((size_t)((b * 4 + t) * CV + v)) << 10) + q);
            s.x += m.x; s.y += m.y; s.z += m.z; s.w += m.w;
        }
        f32x4 cs = *(const f32x4*)(colsum + (b << 10) + q);
        f32x4 o;
        o.x = s.x / cs.x; o.y = s.y / cs.y; o.z = s.z / cs.z; o.w = s.w / cs.w;
        *(f32x4*)(out + (((size_t)(b * 1024 + 512 + v)) << 10) + q) = o;
    }
}

// ---------------------------------------------------------------------------
// K6: qv_out[b][t*128+k][q] = sum_v W[bt][k][v] * QVp[b][v][q] -> out ch 0..511
// 1-D grid 256, XCD-swizzled.
// ---------------------------------------------------------------------------
__global__ __launch_bounds__(256) void k_qvout(const bf16* __restrict__ Wt,
                                               const float* __restrict__ QVp,
                                               float* __restrict__ out) {
    __shared__ __align__(16) char smem[27648];
    bf16* As = (bf16*)smem;              // [128][72]
    bf16* Bs = (bf16*)(smem + 18432);    // [64][72]

    int bid = blockIdx.x;
    int sw  = (bid & 7) * 32 + (bid >> 3);
    const int bt = sw >> 4;
    const int q0 = (sw & 15) * 64;
    const int b = bt >> 2, t = bt & 3;

    const int tid = threadIdx.x;
    const int lane = tid & 63;
    const int wid = tid >> 6;
    const int wr = wid >> 1, wc = wid & 1;
    const int g = lane >> 4, li = lane & 15;

    const bf16*  Abase = Wt + (size_t)bt * CK * CV;
    const float* Bbase = QVp + (((size_t)b * CV) << 10) + q0;

    const f32x4 fz = {0.f, 0.f, 0.f, 0.f};
    f32x4 acc[4][2];
#pragma unroll
    for (int i = 0; i < 4; ++i)
#pragma unroll
        for (int j = 0; j < 2; ++j) acc[i][j] = fz;

    const int ql  = tid & 63;
    const int grp = tid >> 6;

    for (int kk = 0; kk < 8; ++kk) {
        int vk0 = kk * 64;
#pragma unroll
        for (int pass = 0; pass < 4; ++pass) {
            int idx = pass * 256 + tid;
            int row = idx >> 3;
            int ch  = (idx & 7) * 8;
            bf16x8 v = *(const bf16x8*)(Abase + (size_t)row * CV + vk0 + ch);
            *(bf16x8*)(As + row * 72 + ch) = v;
        }
#pragma unroll
        for (int j = 0; j < 8; ++j) {
            int vv = 2 * grp + 8 * j;
            float b0 = Bbase[(size_t)(vk0 + vv) * 1024 + ql];
            float b1 = Bbase[(size_t)(vk0 + vv + 1) * 1024 + ql];
            bf16x2 p; p.x = (bf16)b0; p.y = (bf16)b1;
            *(bf16x2*)(Bs + ql * 72 + vv) = p;
        }
        __syncthreads();
#pragma unroll
        for (int kc = 0; kc < 2; ++kc) {
            bf16x8 af[4], bfr[2];
#pragma unroll
            for (int mf = 0; mf < 4; ++mf)
                af[mf] = *(const bf16x8*)(As + (wr * 64 + mf * 16 + li) * 72 + kc * 32 + g * 8);
#pragma unroll
            for (int nf = 0; nf < 2; ++nf)
                bfr[nf] = *(const bf16x8*)(Bs + (wc * 32 + nf * 16 + li) * 72 + kc * 32 + g * 8);
#pragma unroll
            for (int mf = 0; mf < 4; ++mf)
#pragma unroll
                for (int nf = 0; nf < 2; ++nf)
                    acc[mf][nf] = mfma16(af[mf], bfr[nf], acc[mf][nf]);
        }
        __syncthreads();
    }

#pragma unroll
    for (int mf = 0; mf < 4; ++mf)
#pragma unroll
        for (int nf = 0; nf < 2; ++nf) {
            int k = wr * 64 + mf * 16 + g * 4;
            int q = q0 + wc * 32 + nf * 16 + li;
            f32x4 a = acc[mf][nf];
            size_t base = ((size_t)(b * 1024 + t * 128 + k) << 10) + q;
            out[base]             = a.x;
            out[base + (1 << 10)] = a.y;
            out[base + (2 << 10)] = a.z;
            out[base + (3 << 10)] = a.w;
        }
}

// ---------------------------------------------------------------------------
extern "C" void kernel_launch(void* const* d_in, const int* in_sizes, int n_in,
                              void* d_out, int out_size, void* d_ws, size_t ws_size,
                              hipStream_t stream) {
    (void)in_sizes; (void)n_in; (void)out_size; (void)ws_size;
    const float* mk  = (const float*)d_in[0];  // [T][B][CK][4096]
    const float* mv  = (const float*)d_in[1];  // [T][B][CV][4096]
    const float* qv  = (const float*)d_in[2];  // [B][CV][4096]
    const float* mkl = (const float*)d_in[3];  // [T][B][CK][1024]
    const float* mvl = (const float*)d_in[4];  // [T][B][CV][1024]
    const float* qkl = (const float*)d_in[5];  // [B][CK][1024]
    float* out = (float*)d_out;                // [B][1024][1024]

    char* w = (char*)d_ws;
    bf16*  Pt      = (bf16*)w;  w += (size_t)B_ * QQ * MM * 2;           // 32 MB
    float* QVp     = (float*)w; w += (size_t)B_ * CV * QQ * 4;           // 8 MB
    float* Gp      = (float*)w; w += (size_t)NS * 16 * CK * CV * 4;      // 16 MB
    bf16*  Wt      = (bf16*)w;  w += (size_t)B_ * T_ * CK * CV * 2;      // 2 MB
    float* colsum  = (float*)w; w += (size_t)B_ * QQ * 4;                // 16 KB
    bf16*  Ab      = (bf16*)w;  w += (size_t)T_ * B_ * CV * QQ * 2;      // 16 MB
    float* cs_part = (float*)w; w += (size_t)B_ * 64 * QQ * 4;           // 1 MB
    float* Mp      = (float*)w; w += (size_t)T_ * B_ * CV * QQ * 4;      // 32 MB
    f16*   mkh     = (f16*)w;   w += (size_t)T_ * B_ * CK * PP * 2;      // 16.8 MB
    f16*   mvh     = (f16*)w;   w += (size_t)T_ * B_ * CV * PP * 2;      // 67 MB

    k_stage1<<<dim3(2048), 256, 0, stream>>>(mkl, qkl, Pt, cs_part,
                                             mvl, Ab, qv, QVp,
                                             mk, mkh, mv, mvh);
    k_stage2<<<dim3(784),  256, 0, stream>>>(mkh, mvh, Gp, Ab, Pt, Mp,
                                             cs_part, colsum);
    k_stage3<<<dim3(3072), 256, 0, stream>>>(Gp, Wt, Mp, colsum, out);
    k_qvout <<<dim3(256),  256, 0, stream>>>(Wt, QVp, out);
}

// Round 20
// 134.041 us; speedup vs baseline: 1.1696x; 1.1696x over previous
//
#include <hip/hip_runtime.h>

// Problem constants (fixed by setup_inputs)
#define T_ 4
#define B_ 4
#define CK 128
#define CV 512
#define PP 4096   // H*W = 64*64
#define QQ 1024   // h*w = 32*32
#define MM 4096   // T*h*w
#define NS 4      // gattn K-split factor

using f32x2  = __attribute__((ext_vector_type(2))) float;
using f32x4  = __attribute__((ext_vector_type(4))) float;
using bf16   = __bf16;
using bf16x2 = __attribute__((ext_vector_type(2))) __bf16;
using bf16x4 = __attribute__((ext_vector_type(4))) __bf16;
using bf16x8 = __attribute__((ext_vector_type(8))) __bf16;
using f16    = _Float16;
using f16x8  = __attribute__((ext_vector_type(8))) _Float16;

__device__ __forceinline__ f32x4 mfma16(bf16x8 a, bf16x8 b, f32x4 c) {
    return __builtin_amdgcn_mfma_f32_16x16x32_bf16(a, b, c, 0, 0, 0);
}
__device__ __forceinline__ f32x4 mfma16h(f16x8 a, f16x8 b, f32x4 c) {
    return __builtin_amdgcn_mfma_f32_16x16x32_f16(a, b, c, 0, 0, 0);
}

// async global->LDS DMA, 16B per lane, dest = uniform base + lane*16
__device__ __forceinline__ void gload16(const void* g, void* l) {
    __builtin_amdgcn_global_load_lds(
        (const __attribute__((address_space(1))) void*)g,
        (__attribute__((address_space(3))) void*)l, 16, 0, 0);
}

// ===========================================================================
// STAGE 1 (interleaved roles; logits hides under streaming):
//   bid % 3 == 0 -> logits GEMM (1024 blocks) -> Pt, cs_part
//   else sid = bid - bid/3 - 1:
//     [0,1024)    mv  f32 -> mvh f16  (256 KB contiguous tile/block)
//     [1024,1280) mk  f32 -> mkh f16
//     [1280,1536) mvl f32 -> Ab  bf16
//     [1536,1792) qv 2x2 avg-pool -> QVp (f32x4 reads, 2 outputs/iter)
//     else        idle
// ===========================================================================
__global__ __launch_bounds__(256) void k_stage1(
        const float* __restrict__ mkl, const float* __restrict__ qkl,
        bf16* __restrict__ Pt, float* __restrict__ cs_part,
        const float* __restrict__ mvl, bf16* __restrict__ Ab,
        const float* __restrict__ qv,  float* __restrict__ qvp,
        const float* __restrict__ mk,  f16* __restrict__ mkh,
        const float* __restrict__ mv,  f16* __restrict__ mvh) {
    __shared__ __align__(16) char smem[20480];
    const int bid = blockIdx.x;
    const int tid = threadIdx.x;

    if (bid % 3 == 0) {
        // ---- logits: L = mkl^T qkl, exp, colsums, transpose -> Pt -----------
        bf16* As = (bf16*)smem;              // [128][40]
        bf16* Bs = (bf16*)(smem + 10240);    // [128][40]
        bf16* Th = (bf16*)smem;              // [128][72] half-transpose (union)

        int lb  = bid / 3;                   // 0..1023
        int sw  = (lb & 7) * 128 + (lb >> 3);
        const int b  = sw >> 8;
        const int r  = sw & 255;
        const int qy = r >> 5;
        const int mx = r & 31;
        const int m0 = mx * 128;
        const int q0 = qy * 128;
        const int t  = m0 >> 10;
        const int sm0 = m0 & 1023;

        const int lane = tid & 63;
        const int wid  = tid >> 6;
        const int wr = wid >> 1, wc = wid & 1;
        const int g = lane >> 4, li = lane & 15;

        const float* Abase = mkl + (((size_t)(t * B_ + b) * CK) << 10) + sm0;
        const float* Bbase = qkl + (((size_t)b * CK) << 10) + q0;
        const int ml   = tid & 127;
        const int half = tid >> 7;

        const f32x4 fz = {0.f, 0.f, 0.f, 0.f};
        f32x4 acc[4][4];
#pragma unroll
        for (int i = 0; i < 4; ++i)
#pragma unroll
            for (int j = 0; j < 4; ++j) acc[i][j] = fz;

        for (int k0 = 0; k0 < CK; k0 += 32) {
#pragma unroll
            for (int j = 0; j < 8; ++j) {
                int kk = 4 * j + 2 * half;
                float a0 = Abase[(k0 + kk) * 1024 + ml];
                float a1 = Abase[(k0 + kk + 1) * 1024 + ml];
                bf16x2 pa; pa.x = (bf16)a0; pa.y = (bf16)a1;
                *(bf16x2*)(As + ml * 40 + kk) = pa;
                float b0 = Bbase[(k0 + kk) * 1024 + ml];
                float b1 = Bbase[(k0 + kk + 1) * 1024 + ml];
                bf16x2 pb; pb.x = (bf16)b0; pb.y = (bf16)b1;
                *(bf16x2*)(Bs + ml * 40 + kk) = pb;
            }
            __syncthreads();
            bf16x8 af[4], bfr[4];
#pragma unroll
            for (int mf = 0; mf < 4; ++mf)
                af[mf] = *(const bf16x8*)(As + (wr * 64 + mf * 16 + li) * 40 + g * 8);
#pragma unroll
            for (int nf = 0; nf < 4; ++nf)
                bfr[nf] = *(const bf16x8*)(Bs + (wc * 64 + nf * 16 + li) * 40 + g * 8);
#pragma unroll
            for (int mf = 0; mf < 4; ++mf)
#pragma unroll
                for (int nf = 0; nf < 4; ++nf)
                    acc[mf][nf] = mfma16(af[mf], bfr[nf], acc[mf][nf]);
            __syncthreads();
        }

        float cs[4] = {0.f, 0.f, 0.f, 0.f};
        bf16x4 ebuf[4][4];
#pragma unroll
        for (int mf = 0; mf < 4; ++mf)
#pragma unroll
            for (int nf = 0; nf < 4; ++nf) {
                f32x4 v = acc[mf][nf];
                float e0 = __expf(v.x), e1 = __expf(v.y);
                float e2 = __expf(v.z), e3 = __expf(v.w);
                cs[nf] += e0 + e1 + e2 + e3;
                bf16x4 e; e.x = (bf16)e0; e.y = (bf16)e1; e.z = (bf16)e2; e.w = (bf16)e3;
                ebuf[mf][nf] = e;
            }
#pragma unroll
        for (int nf = 0; nf < 4; ++nf) {
            float s = cs[nf];
            s += __shfl_xor(s, 16);
            s += __shfl_xor(s, 32);
            if (g == 0)
                cs_part[(size_t)(((b * 32 + mx) * 2 + wr) << 10) + q0 + wc * 64 + nf * 16 + li] = s;
        }
#pragma unroll
        for (int p = 0; p < 2; ++p) {
            __syncthreads();
            if (wr == p) {
#pragma unroll
                for (int mf = 0; mf < 4; ++mf)
#pragma unroll
                    for (int nf = 0; nf < 4; ++nf) {
                        int col  = wc * 64 + nf * 16 + li;
                        int rowb = mf * 16 + g * 4;
                        *(bf16x4*)(Th + col * 72 + rowb) = ebuf[mf][nf];
                    }
            }
            __syncthreads();
#pragma unroll
            for (int pass = 0; pass < 4; ++pass) {
                int idx = pass * 256 + tid;
                int row = idx >> 3;
                int ch  = (idx & 7) * 8;
                bf16x8 v = *(const bf16x8*)(Th + row * 72 + ch);
                *(bf16x8*)(Pt + (size_t)(b * QQ + q0 + row) * MM + m0 + p * 64 + ch) = v;
            }
        }
    } else {
        int sid = bid - bid / 3 - 1;           // 0..2047
        if (sid < 1024) {
            // ---- mv -> mvh ---------------------------------------------------
            int base = sid * 4096 + tid;
#pragma unroll
            for (int i = 0; i < 16; ++i) {
                int idx = base + i * 256;
                f32x4 a = __builtin_nontemporal_load((const f32x4*)mv + (size_t)idx * 2);
                f32x4 c = __builtin_nontemporal_load((const f32x4*)mv + (size_t)idx * 2 + 1);
                f16x8 o;
                o[0] = (f16)a.x; o[1] = (f16)a.y; o[2] = (f16)a.z; o[3] = (f16)a.w;
                o[4] = (f16)c.x; o[5] = (f16)c.y; o[6] = (f16)c.z; o[7] = (f16)c.w;
                ((f16x8*)mvh)[idx] = o;
            }
        } else if (sid < 1280) {
            // ---- mk -> mkh ---------------------------------------------------
            int base = (sid - 1024) * 4096 + tid;
#pragma unroll
            for (int i = 0; i < 16; ++i) {
                int idx = base + i * 256;
                f32x4 a = __builtin_nontemporal_load((const f32x4*)mk + (size_t)idx * 2);
                f32x4 c = __builtin_nontemporal_load((const f32x4*)mk + (size_t)idx * 2 + 1);
                f16x8 o;
                o[0] = (f16)a.x; o[1] = (f16)a.y; o[2] = (f16)a.z; o[3] = (f16)a.w;
                o[4] = (f16)c.x; o[5] = (f16)c.y; o[6] = (f16)c.z; o[7] = (f16)c.w;
                ((f16x8*)mkh)[idx] = o;
            }
        } else if (sid < 1536) {
            // ---- mvl -> Ab bf16 ----------------------------------------------
            int base = (sid - 1280) * 4096 + tid;
#pragma unroll
            for (int i = 0; i < 16; ++i) {
                int idx = base + i * 256;
                f32x4 a = __builtin_nontemporal_load((const f32x4*)mvl + (size_t)idx * 2);
                f32x4 c = __builtin_nontemporal_load((const f32x4*)mvl + (size_t)idx * 2 + 1);
                bf16x8 o;
                o[0] = (bf16)a.x; o[1] = (bf16)a.y; o[2] = (bf16)a.z; o[3] = (bf16)a.w;
                o[4] = (bf16)c.x; o[5] = (bf16)c.y; o[6] = (bf16)c.z; o[7] = (bf16)c.w;
                ((bf16x8*)Ab)[idx] = o;
            }
        } else if (sid < 1792) {
            // ---- qv 2x2 avg-pool, f32x4 reads, 2 outputs/iter ----------------
            int base = (sid - 1536) * 4096 + tid;   // pair index
#pragma unroll
            for (int i = 0; i < 16; ++i) {
                int pidx = base + i * 256;          // 0..1048575
                int pr = pidx & 511;
                int bv = pidx >> 9;
                int y = pr >> 4, xp = pr & 15;
                const float* src = qv + ((size_t)bv << 12) + y * 128 + xp * 4;
                f32x4 r0 = __builtin_nontemporal_load((const f32x4*)src);
                f32x4 r1 = __builtin_nontemporal_load((const f32x4*)(src + 64));
                f32x2 o;
                o.x = 0.25f * (r0.x + r0.y + r1.x + r1.y);
                o.y = 0.25f * (r0.z + r0.w + r1.z + r1.w);
                *(f32x2*)(qvp + ((size_t)bv << 10) + y * 32 + xp * 2) = o;
            }
        }
        // else: idle filler block
    }
}

// ===========================================================================
// STAGE 2:  [0,256)     gattn GEMM (f16 data, NS=4) -> Gp
//           [256,768)   memory GEMM -> Mp
//           [768,784)   colsum reduce
// ===========================================================================
__global__ __launch_bounds__(256, 2) void k_stage2(
        const f16* __restrict__ mkh, const f16* __restrict__ mvh,
        float* __restrict__ Gp,
        const bf16* __restrict__ Ab, const bf16* __restrict__ Pt,
        float* __restrict__ Mp,
        const float* __restrict__ cs_part, float* __restrict__ colsum) {
    __shared__ __align__(16) char smem[65536];
    const int bid = blockIdx.x;
    const int tid = threadIdx.x;

    if (bid < 256) {
        // ---- gattn: G[k][v] = sum_p mkh*mvh  (f16 MFMA), NS=4 ---------------
        f16* lsA = (f16*)smem;               // [2][128*64]
        f16* lsB = (f16*)(smem + 32768);

        int sw  = (bid & 7) * 32 + (bid >> 3);
        const int bt = sw >> 4;
        const int rx = sw & 15;
        const int ks = rx >> 2;              // 0..3, p-range [ks*1024, +1024)
        const int v0 = (rx & 3) * 128;
        const int b = bt >> 2, t = bt & 3;

        const int lane = tid & 63;
        const int w    = tid >> 6;
        const int wr = w >> 1, wc = w & 1;
        const int g = lane >> 4, li = lane & 15;
        const int rr = lane >> 3;
        const int cg = (lane & 7) ^ rr;

        const f16* Abase = mkh + ((size_t)(t * B_ + b) * CK) * PP + ks * 1024;
        const f16* Bbase = mvh + ((size_t)((t * B_ + b) * CV + v0)) * PP + ks * 1024;

        auto STAGE = [&](int buf, int j) {
            int mg = j * 64;
#pragma unroll
            for (int cc = 0; cc < 4; ++cc) {
                int c = cc * 4 + w;
                int r = c * 8 + rr;
                gload16(Abase + (size_t)r * PP + mg + cg * 8, lsA + buf * 8192 + c * 512);
                gload16(Bbase + (size_t)r * PP + mg + cg * 8, lsB + buf * 8192 + c * 512);
            }
        };
        auto FRAG = [&](const f16* base, int r, int G) -> f16x8 {
            int x = r & 7;
            return *(const f16x8*)(base + (r >> 3) * 512 + x * 64 + ((G ^ x) * 8));
        };

        const f32x4 fz = {0.f, 0.f, 0.f, 0.f};
        f32x4 acc[4][4];
#pragma unroll
        for (int i = 0; i < 4; ++i)
#pragma unroll
            for (int j = 0; j < 4; ++j) acc[i][j] = fz;

        STAGE(0, 0);
        __syncthreads();
        int cur = 0;

        for (int j = 0; j < 16; ++j) {
            if (j + 1 < 16) STAGE(cur ^ 1, j + 1);
#pragma unroll
            for (int kc = 0; kc < 2; ++kc) {
                f16x8 af[4], bfr[4];
#pragma unroll
                for (int mf = 0; mf < 4; ++mf)
                    af[mf] = FRAG(lsA + cur * 8192, wr * 64 + mf * 16 + li, kc * 4 + g);
#pragma unroll
                for (int nf = 0; nf < 4; ++nf)
                    bfr[nf] = FRAG(lsB + cur * 8192, wc * 64 + nf * 16 + li, kc * 4 + g);
#pragma unroll
                for (int mf = 0; mf < 4; ++mf)
#pragma unroll
                    for (int nf = 0; nf < 4; ++nf)
                        acc[mf][nf] = mfma16h(af[mf], bfr[nf], acc[mf][nf]);
            }
            __syncthreads();
            cur ^= 1;
        }

        float* outp = Gp + (size_t)(ks * 16 + bt) * CK * CV + v0;
#pragma unroll
        for (int mf = 0; mf < 4; ++mf)
#pragma unroll
            for (int nf = 0; nf < 4; ++nf) {
                int k = wr * 64 + mf * 16 + g * 4;
                int v = wc * 64 + nf * 16 + li;
                f32x4 a = acc[mf][nf];
                outp[(size_t)(k + 0) * CV + v] = a.x;
                outp[(size_t)(k + 1) * CV + v] = a.y;
                outp[(size_t)(k + 2) * CV + v] = a.z;
                outp[(size_t)(k + 3) * CV + v] = a.w;
            }
    } else if (bid < 768) {
        // ---- memory: Mp = Ab x Pt (bf16 MFMA) -------------------------------
        bf16* lsA = (bf16*)smem;             // [2][128*64]
        bf16* lsB = (bf16*)(smem + 32768);

        int mb = bid - 256;
        int sw  = (mb & 7) * 64 + (mb >> 3);
        const int bt = sw >> 5;
        const int rx = sw & 31;
        const int q0 = (rx >> 2) * 128;
        const int v0 = (rx & 3) * 128;
        const int b = bt >> 2, t = bt & 3;

        const int lane = tid & 63;
        const int w    = tid >> 6;
        const int wr = w >> 1, wc = w & 1;
        const int g = lane >> 4, li = lane & 15;
        const int rr = lane >> 3;
        const int cg = (lane & 7) ^ rr;

        const bf16* Abase = Ab + (((size_t)((t * B_ + b) * CV + v0)) << 10);
        const bf16* Bbase = Pt + (size_t)(b * QQ + q0) * MM + t * 1024;

        auto STAGE = [&](int buf, int j) {
            int mg = j * 64;
#pragma unroll
            for (int cc = 0; cc < 4; ++cc) {
                int c = cc * 4 + w;
                int r = c * 8 + rr;
                gload16(Abase + (size_t)r * 1024 + mg + cg * 8, lsA + buf * 8192 + c * 512);
                gload16(Bbase + (size_t)r * MM   + mg + cg * 8, lsB + buf * 8192 + c * 512);
            }
        };
        auto FRAG = [&](const bf16* base, int r, int G) -> bf16x8 {
            int x = r & 7;
            return *(const bf16x8*)(base + (r >> 3) * 512 + x * 64 + ((G ^ x) * 8));
        };

        const f32x4 fz = {0.f, 0.f, 0.f, 0.f};
        f32x4 acc[4][4];
#pragma unroll
        for (int i = 0; i < 4; ++i)
#pragma unroll
            for (int j = 0; j < 4; ++j) acc[i][j] = fz;

        STAGE(0, 0);
        __syncthreads();
        int cur = 0;

        for (int j = 0; j < 16; ++j) {
            if (j + 1 < 16) STAGE(cur ^ 1, j + 1);
#pragma unroll
            for (int kc = 0; kc < 2; ++kc) {
                bf16x8 af[4], bfr[4];
#pragma unroll
                for (int mf = 0; mf < 4; ++mf)
                    af[mf] = FRAG(lsA + cur * 8192, wr * 64 + mf * 16 + li, kc * 4 + g);
#pragma unroll
                for (int nf = 0; nf < 4; ++nf)
                    bfr[nf] = FRAG(lsB + cur * 8192, wc * 64 + nf * 16 + li, kc * 4 + g);
#pragma unroll
                for (int mf = 0; mf < 4; ++mf)
#pragma unroll
                    for (int nf = 0; nf < 4; ++nf)
                        acc[mf][nf] = mfma16(af[mf], bfr[nf], acc[mf][nf]);
            }
            __syncthreads();
            cur ^= 1;
        }

#pragma unroll
        for (int nf = 0; nf < 4; ++nf) {
            int q = q0 + wc * 64 + nf * 16 + li;
#pragma unroll
            for (int mf = 0; mf < 4; ++mf) {
                int v = v0 + wr * 64 + mf * 16 + g * 4;
                f32x4 a = acc[mf][nf];
                float* base = Mp + (((size_t)bt * CV + v) << 10) + q;
                base[0 << 10] = a.x;
                base[1 << 10] = a.y;
                base[2 << 10] = a.z;
                base[3 << 10] = a.w;
            }
        }
    } else {
        // ---- colsum: sum 64 partial rows ------------------------------------
        int idx = (bid - 768) * 256 + tid;   // B*QQ = 4096
        int q = idx & (QQ - 1);
        int b = idx >> 10;
        float s = 0.f;
#pragma unroll 8
        for (int r = 0; r < 64; ++r)
            s += cs_part[(size_t)(((b * 64 + r)) << 10) + q];
        colsum[idx] = s;
    }
}

// ===========================================================================
// STAGE 3:  [0,1024)     softT: reduce NS partials + softmax over T -> Wt
//           [1024,3072)  reduce: out[512..1023] = sum_t Mp / colsum
// ===========================================================================
__global__ __launch_bounds__(256) void k_stage3(
        const float* __restrict__ Gp, bf16* __restrict__ Wt,
        const float* __restrict__ Mp, const float* __restrict__ colsum,
        float* __restrict__ out) {
    const int bid = blockIdx.x;
    const int tid = threadIdx.x;

    if (bid < 1024) {
        int idx = bid * 256 + tid;             // B*CK*CV = 262144
        int v = idx & (CV - 1);
        int bk = idx >> 9;
        int k = bk & (CK - 1);
        int b = bk >> 7;
        float gv[4];
#pragma unroll
        for (int t = 0; t < 4; ++t) {
            float s = 0.f;
#pragma unroll
            for (int ks = 0; ks < NS; ++ks)
                s += Gp[((size_t)(ks * 16 + b * 4 + t) * CK + k) * CV + v];
            gv[t] = s;
        }
        float mx = fmaxf(fmaxf(gv[0], gv[1]), fmaxf(gv[2], gv[3]));
        float e[4], sum = 0.f;
#pragma unroll
        for (int t = 0; t < 4; ++t) { e[t] = __expf(gv[t] - mx); sum += e[t]; }
        float inv = 1.f / sum;
#pragma unroll
        for (int t = 0; t < 4; ++t)
            Wt[((size_t)((b * 4 + t) * CK + k)) * CV + v] = (bf16)(e[t] * inv);
    } else {
        int idx = ((bid - 1024) * 256 + tid) * 4;   // over B*CV*QQ = 2M
        int q = idx & (QQ - 1);
        int v = (idx >> 10) & (CV - 1);
        int b = idx >> 19;
        f32x4 s = {0.f, 0.f, 0.f, 0.f};
#pragma unroll
        for (int t = 0; t < 4; ++t) {
            f32x4 m = *(const f32x4*)(Mp + (((size_t)((b * 4 + t) * CV + v)) << 10) + q);
            s.x += m.x; s.y += m.y; s.z += m.z; s.w += m.w;
        }
        f32x4 cs = *(const f32x4*)(colsum + (b << 10) + q);
        f32x4 o;
        o.x = s.x / cs.x; o.y = s.y / cs.y; o.z = s.z / cs.z; o.w = s.w / cs.w;
        *(f32x4*)(out + (((size_t)(b * 1024 + 512 + v)) << 10) + q) = o;
    }
}

// ---------------------------------------------------------------------------
// K6: qv_out[b][t*128+k][q] = sum_v W[bt][k][v] * QVp[b][v][q] -> out ch 0..511
// 1-D grid 256, XCD-swizzled.
// ---------------------------------------------------------------------------
__global__ __launch_bounds__(256) void k_qvout(const bf16* __restrict__ Wt,
                                               const float* __restrict__ QVp,
                                               float* __restrict__ out) {
    __shared__ __align__(16) char smem[27648];
    bf16* As = (bf16*)smem;              // [128][72]
    bf16* Bs = (bf16*)(smem + 18432);    // [64][72]

    int bid = blockIdx.x;
    int sw  = (bid & 7) * 32 + (bid >> 3);
    const int bt = sw >> 4;
    const int q0 = (sw & 15) * 64;
    const int b = bt >> 2, t = bt & 3;

    const int tid = threadIdx.x;
    const int lane = tid & 63;
    const int wid = tid >> 6;
    const int wr = wid >> 1, wc = wid & 1;
    const int g = lane >> 4, li = lane & 15;

    const bf16*  Abase = Wt + (size_t)bt * CK * CV;
    const float* Bbase = QVp + (((size_t)b * CV) << 10) + q0;

    const f32x4 fz = {0.f, 0.f, 0.f, 0.f};
    f32x4 acc[4][2];
#pragma unroll
    for (int i = 0; i < 4; ++i)
#pragma unroll
        for (int j = 0; j < 2; ++j) acc[i][j] = fz;

    const int ql  = tid & 63;
    const int grp = tid >> 6;

    for (int kk = 0; kk < 8; ++kk) {
        int vk0 = kk * 64;
#pragma unroll
        for (int pass = 0; pass < 4; ++pass) {
            int idx = pass * 256 + tid;
            int row = idx >> 3;
            int ch  = (idx & 7) * 8;
            bf16x8 v = *(const bf16x8*)(Abase + (size_t)row * CV + vk0 + ch);
            *(bf16x8*)(As + row * 72 + ch) = v;
        }
#pragma unroll
        for (int j = 0; j < 8; ++j) {
            int vv = 2 * grp + 8 * j;
            float b0 = Bbase[(size_t)(vk0 + vv) * 1024 + ql];
            float b1 = Bbase[(size_t)(vk0 + vv + 1) * 1024 + ql];
            bf16x2 p; p.x = (bf16)b0; p.y = (bf16)b1;
            *(bf16x2*)(Bs + ql * 72 + vv) = p;
        }
        __syncthreads();
#pragma unroll
        for (int kc = 0; kc < 2; ++kc) {
            bf16x8 af[4], bfr[2];
#pragma unroll
            for (int mf = 0; mf < 4; ++mf)
                af[mf] = *(const bf16x8*)(As + (wr * 64 + mf * 16 + li) * 72 + kc * 32 + g * 8);
#pragma unroll
            for (int nf = 0; nf < 2; ++nf)
                bfr[nf] = *(const bf16x8*)(Bs + (wc * 32 + nf * 16 + li) * 72 + kc * 32 + g * 8);
#pragma unroll
            for (int mf = 0; mf < 4; ++mf)
#pragma unroll
                for (int nf = 0; nf < 2; ++nf)
                    acc[mf][nf] = mfma16(af[mf], bfr[nf], acc[mf][nf]);
        }
        __syncthreads();
    }

#pragma unroll
    for (int mf = 0; mf < 4; ++mf)
#pragma unroll
        for (int nf = 0; nf < 2; ++nf) {
            int k = wr * 64 + mf * 16 + g * 4;
            int q = q0 + wc * 32 + nf * 16 + li;
            f32x4 a = acc[mf][nf];
            size_t base = ((size_t)(b * 1024 + t * 128 + k) << 10) + q;
            out[base]             = a.x;
            out[base + (1 << 10)] = a.y;
            out[base + (2 << 10)] = a.z;
            out[base + (3 << 10)] = a.w;
        }
}

// ---------------------------------------------------------------------------
extern "C" void kernel_launch(void* const* d_in, const int* in_sizes, int n_in,
                              void* d_out, int out_size, void* d_ws, size_t ws_size,
                              hipStream_t stream) {
    (void)in_sizes; (void)n_in; (void)out_size; (void)ws_size;
    const float* mk  = (const float*)d_in[0];  // [T][B][CK][4096]
    const float* mv  = (const float*)d_in[1];  // [T][B][CV][4096]
    const float* qv  = (const float*)d_in[2];  // [B][CV][4096]
    const float* mkl = (const float*)d_in[3];  // [T][B][CK][1024]
    const float* mvl = (const float*)d_in[4];  // [T][B][CV][1024]
    const float* qkl = (const float*)d_in[5];  // [B][CK][1024]
    float* out = (float*)d_out;                // [B][1024][1024]

    char* w = (char*)d_ws;
    bf16*  Pt      = (bf16*)w;  w += (size_t)B_ * QQ * MM * 2;           // 32 MB
    float* QVp     = (float*)w; w += (size_t)B_ * CV * QQ * 4;           // 8 MB
    float* Gp      = (float*)w; w += (size_t)NS * 16 * CK * CV * 4;      // 16 MB
    bf16*  Wt      = (bf16*)w;  w += (size_t)B_ * T_ * CK * CV * 2;      // 2 MB
    float* colsum  = (float*)w; w += (size_t)B_ * QQ * 4;                // 16 KB
    bf16*  Ab      = (bf16*)w;  w += (size_t)T_ * B_ * CV * QQ * 2;      // 16 MB
    float* cs_part = (float*)w; w += (size_t)B_ * 64 * QQ * 4;           // 1 MB
    float* Mp      = (float*)w; w += (size_t)T_ * B_ * CV * QQ * 4;      // 32 MB
    f16*   mkh     = (f16*)w;   w += (size_t)T_ * B_ * CK * PP * 2;      // 16.8 MB
    f16*   mvh     = (f16*)w;   w += (size_t)T_ * B_ * CV * PP * 2;      // 67 MB

    k_stage1<<<dim3(3072), 256, 0, stream>>>(mkl, qkl, Pt, cs_part,
                                             mvl, Ab, qv, QVp,
                                             mk, mkh, mv, mvh);
    k_stage2<<<dim3(784),  256, 0, stream>>>(mkh, mvh, Gp, Ab, Pt, Mp,
                                             cs_part, colsum);
    k_stage3<<<dim3(3072), 256, 0, stream>>>(Gp, Wt, Mp, colsum, out);
    k_qvout <<<dim3(256),  256, 0, stream>>>(Wt, QVp, out);
}